// Round 2
// baseline (4436.981 us; speedup 1.0000x reference)
//
#include <hip/hip_runtime.h>
#include <hip/hip_bf16.h>

#define D_MODEL 768
#define NH 12
#define DK 64
#define RQ 6
#define RK 2
#define RV 2
#define BATCH 8
#define SEQ 4096
#define NPOS (BATCH*SEQ)

// Runtime-dtype load: flag isbf==1 -> buffer holds bf16, else fp32.
__device__ __forceinline__ float ldf(const void* p, size_t i, int isbf) {
    if (isbf) return __bfloat162float(((const __hip_bfloat16*)p)[i]);
    return ((const float*)p)[i];
}

// ---------------------------------------------------------------------------
// Dtype detector: scan first 8192 16-bit words of x for bf16 Inf/NaN exponent
// pattern. fp32 N(0,1) data -> ~16 hits; real bf16 data -> 0 hits.
// flag = 1 (bf16) iff zero hits.
// ---------------------------------------------------------------------------
__global__ void detect_dtype(const unsigned short* __restrict__ x, int* flag) {
    __shared__ int cnt;
    if (threadIdx.x == 0) cnt = 0;
    __syncthreads();
    int c = 0;
    for (int i = threadIdx.x; i < 8192; i += 256) {
        unsigned short w = x[i];
        if ((w & 0x7F80) == 0x7F80) c++;
    }
    if (c) atomicAdd(&cnt, c);
    __syncthreads();
    if (threadIdx.x == 0) *flag = (cnt == 0) ? 1 : 0;
}

// ---------------------------------------------------------------------------
// Kernel 1: per-position fused projections + tensor-product + head-attention.
// One block (256 threads) per (b,s) position. O stored bf16 (internal) with
// layout [b][h][s][d]: flat view equals transpose(0,2,1,3).reshape(b,s,768).
// ---------------------------------------------------------------------------
__global__ __launch_bounds__(256) void tpa_pos(
    const void* __restrict__ x,
    const void* __restrict__ rope_pos,
    const void* __restrict__ Waq, const void* __restrict__ baq,
    const void* __restrict__ Wbq, const void* __restrict__ bbq,
    const void* __restrict__ Wak, const void* __restrict__ bak,
    const void* __restrict__ Wbk, const void* __restrict__ bbk,
    const void* __restrict__ Wav, const void* __restrict__ bav,
    const void* __restrict__ Wbv, const void* __restrict__ bbv,
    const int* __restrict__ flag,
    __hip_bfloat16* __restrict__ O)
{
    const int isbf = *flag;
    const int pos = blockIdx.x;
    const int b = pos >> 12;     // / SEQ
    const int s = pos & 4095;    // % SEQ
    const int t = threadIdx.x;

    __shared__ float xr[D_MODEL];
    __shared__ float rp[DK];
    __shared__ float proj[760];      // aq[72] bq[384] ak[24] bk[128] av[24] bv[128]
    __shared__ float Qs[NH*DK];
    __shared__ float Ks[NH*DK];
    __shared__ float Vs[NH*DK];
    __shared__ float sc[NH*NH];

    for (int i = t; i < D_MODEL; i += 256)
        xr[i] = ldf(x, (size_t)pos*D_MODEL + i, isbf);
    if (t < DK)
        rp[t] = ldf(rope_pos, (size_t)s*DK + t, isbf);
    __syncthreads();

    // --- 760 projection outputs, concatenated ---
    for (int j = t; j < 760; j += 256) {
        const void* W; const void* bias; int cols, col; bool dorope;
        if (j < 72)       { W=Waq; bias=baq; cols=72;  col=j;     dorope=false; }
        else if (j < 456) { W=Wbq; bias=bbq; cols=384; col=j-72;  dorope=true;  }
        else if (j < 480) { W=Wak; bias=bak; cols=24;  col=j-456; dorope=false; }
        else if (j < 608) { W=Wbk; bias=bbk; cols=128; col=j-480; dorope=true;  }
        else if (j < 632) { W=Wav; bias=bav; cols=24;  col=j-608; dorope=false; }
        else              { W=Wbv; bias=bbv; cols=128; col=j-632; dorope=false; }
        float acc = ldf(bias, col, isbf);
        for (int i = 0; i < D_MODEL; ++i)
            acc = fmaf(xr[i], ldf(W, (size_t)i*cols + col, isbf), acc);
        if (dorope) acc *= rp[col & 63];   // cols of B_Q/B_K are (r*64+d); rope on d
        proj[j] = acc;
    }
    __syncthreads();

    const float* aq = proj;
    const float* bq = proj + 72;
    const float* ak = proj + 456;
    const float* bk = proj + 480;
    const float* av = proj + 608;
    const float* bv = proj + 632;

    // --- tensor products: Q/K/V[h][d] = sum_r A[r][h]*B[r][d] ---
    for (int j = t; j < NH*DK; j += 256) {
        int h = j >> 6, d = j & 63;
        float q = 0.f, k = 0.f, v = 0.f;
        #pragma unroll
        for (int r = 0; r < RQ; ++r) q = fmaf(aq[r*NH + h], bq[r*DK + d], q);
        #pragma unroll
        for (int r = 0; r < RK; ++r) k = fmaf(ak[r*NH + h], bk[r*DK + d], k);
        #pragma unroll
        for (int r = 0; r < RV; ++r) v = fmaf(av[r*NH + h], bv[r*DK + d], v);
        Qs[j] = q; Ks[j] = k; Vs[j] = v;
    }
    __syncthreads();

    // --- head-to-head scores (12x12) ---
    if (t < NH*NH) {
        int h = t / NH, g = t % NH;
        float acc = 0.f;
        #pragma unroll
        for (int d = 0; d < DK; ++d) acc = fmaf(Qs[h*DK+d], Ks[g*DK+d], acc);
        sc[t] = acc * 0.125f;   // 1/sqrt(64)
    }
    __syncthreads();

    // --- softmax over g, one thread per row h ---
    if (t < NH) {
        float m = -1e30f;
        for (int g = 0; g < NH; ++g) m = fmaxf(m, sc[t*NH+g]);
        float sum = 0.f;
        for (int g = 0; g < NH; ++g) { float e = __expf(sc[t*NH+g]-m); sc[t*NH+g] = e; sum += e; }
        float inv = 1.0f / sum;
        for (int g = 0; g < NH; ++g) sc[t*NH+g] *= inv;
    }
    __syncthreads();

    // --- out[h][d] = sum_g attn[h][g]*V[g][d]; store to O[b][h][s][d] ---
    for (int j = t; j < NH*DK; j += 256) {
        int h = j >> 6, d = j & 63;
        float acc = 0.f;
        #pragma unroll
        for (int g = 0; g < NH; ++g) acc = fmaf(sc[h*NH+g], Vs[g*DK+d], acc);
        O[((size_t)b*NH + h)*SEQ*DK + (size_t)s*DK + d] = __float2bfloat16(acc);
    }
}

// ---------------------------------------------------------------------------
// Kernel 2: Y = O(32768x768) @ W_out(768x768) + b_out.
// 64x64 tile per block, BK=16, 4x4 per thread, fp32 accumulate.
// O is internal bf16; Wo/bo/Y follow the runtime dtype flag.
// ---------------------------------------------------------------------------
__global__ __launch_bounds__(256) void out_gemm(
    const __hip_bfloat16* __restrict__ A,
    const void* __restrict__ Wo,
    const void* __restrict__ bo,
    const int* __restrict__ flag,
    void* __restrict__ Y)
{
    const int isbf = *flag;
    const int bx = blockIdx.x;   // col tile (12)
    const int by = blockIdx.y;   // row tile (512)
    const int t = threadIdx.x;
    const int tx = t & 15, ty = t >> 4;
    const int row0 = by*64, col0 = bx*64;

    __shared__ float As[64][17];
    __shared__ float Bs[16][68];

    float acc[4][4] = {};

    for (int k0 = 0; k0 < 768; k0 += 16) {
        __syncthreads();
        {   // A tile: 64 rows x 16 k (A is always bf16 internal)
            int r  = t >> 2;
            int kk = (t & 3) * 4;
            const __hip_bfloat16* p = A + (size_t)(row0 + r)*768 + k0 + kk;
            As[r][kk+0] = __bfloat162float(p[0]);
            As[r][kk+1] = __bfloat162float(p[1]);
            As[r][kk+2] = __bfloat162float(p[2]);
            As[r][kk+3] = __bfloat162float(p[3]);
        }
        {   // B tile: 16 k x 64 cols
            int r = t >> 4;
            int c = (t & 15) * 4;
            size_t base = (size_t)(k0 + r)*768 + col0 + c;
            Bs[r][c+0] = ldf(Wo, base+0, isbf);
            Bs[r][c+1] = ldf(Wo, base+1, isbf);
            Bs[r][c+2] = ldf(Wo, base+2, isbf);
            Bs[r][c+3] = ldf(Wo, base+3, isbf);
        }
        __syncthreads();
        #pragma unroll
        for (int kk = 0; kk < 16; ++kk) {
            float a[4], bb[4];
            #pragma unroll
            for (int i = 0; i < 4; ++i) a[i]  = As[ty*4+i][kk];
            #pragma unroll
            for (int j = 0; j < 4; ++j) bb[j] = Bs[kk][tx*4+j];
            #pragma unroll
            for (int i = 0; i < 4; ++i)
                #pragma unroll
                for (int j = 0; j < 4; ++j)
                    acc[i][j] = fmaf(a[i], bb[j], acc[i][j]);
        }
    }

    #pragma unroll
    for (int i = 0; i < 4; ++i) {
        int row = row0 + ty*4 + i;
        #pragma unroll
        for (int j = 0; j < 4; ++j) {
            int col = col0 + tx*4 + j;
            float v = acc[i][j] + ldf(bo, col, isbf);
            size_t idx = (size_t)row*768 + col;
            if (isbf) ((__hip_bfloat16*)Y)[idx] = __float2bfloat16(v);
            else      ((float*)Y)[idx] = v;
        }
    }
}

extern "C" void kernel_launch(void* const* d_in, const int* in_sizes, int n_in,
                              void* d_out, int out_size, void* d_ws, size_t ws_size,
                              hipStream_t stream) {
    const void* x    = d_in[0];
    const void* rope = d_in[1];
    const void* Waq  = d_in[2];
    const void* baq  = d_in[3];
    const void* Wbq  = d_in[4];
    const void* bbq  = d_in[5];
    const void* Wak  = d_in[6];
    const void* bak  = d_in[7];
    const void* Wbk  = d_in[8];
    const void* bbk  = d_in[9];
    const void* Wav  = d_in[10];
    const void* bav  = d_in[11];
    const void* Wbv  = d_in[12];
    const void* bbv  = d_in[13];
    const void* Wo   = d_in[14];
    const void* bo   = d_in[15];

    int* flag = (int*)d_ws;                                 // dtype flag
    __hip_bfloat16* O = (__hip_bfloat16*)((char*)d_ws + 256); // 50.3 MB bf16

    detect_dtype<<<1, 256, 0, stream>>>((const unsigned short*)x, flag);

    tpa_pos<<<NPOS, 256, 0, stream>>>(x, rope, Waq, baq, Wbq, bbq,
                                      Wak, bak, Wbk, bbk, Wav, bav, Wbv, bbv,
                                      flag, O);

    dim3 g2(768/64, NPOS/64);
    out_gemm<<<g2, 256, 0, stream>>>(O, Wo, bo, flag, d_out);
}

// Round 4
// 476.337 us; speedup vs baseline: 9.3148x; 9.3148x over previous
//
#include <hip/hip_runtime.h>
#include <hip/hip_bf16.h>

#define D_MODEL 768
#define NH 12
#define DK 64
#define RQ 6
#define RK 2
#define RV 2
#define BATCH 8
#define SEQ 4096
#define NPOS (BATCH*SEQ)

typedef _Float16 v8h __attribute__((ext_vector_type(8)));
typedef float v4f __attribute__((ext_vector_type(4)));

// ---------------------------------------------------------------------------
// Repack (fp32 -> fp16): WcatT[n][k] = concat-weights transposed, bcat[n] fp32;
// WoT[n][k] = Wo[k][n]. n in [760,768) zero-padded.
// ---------------------------------------------------------------------------
__global__ __launch_bounds__(256) void repack(
    const float* __restrict__ Waq, const float* __restrict__ baq,
    const float* __restrict__ Wbq, const float* __restrict__ bbq,
    const float* __restrict__ Wak, const float* __restrict__ bak,
    const float* __restrict__ Wbk, const float* __restrict__ bbk,
    const float* __restrict__ Wav, const float* __restrict__ bav,
    const float* __restrict__ Wbv, const float* __restrict__ bbv,
    const float* __restrict__ Wo,
    _Float16* __restrict__ WcatT, _Float16* __restrict__ WoT,
    float* __restrict__ bcat)
{
    const int n = blockIdx.x;   // 0..767
    const int t = threadIdx.x;
    const float* W = nullptr; const float* bsrc = nullptr;
    int cols = 0, col = 0;
    if      (n <  72) { W=Waq; bsrc=baq; cols=72;  col=n;     }
    else if (n < 456) { W=Wbq; bsrc=bbq; cols=384; col=n-72;  }
    else if (n < 480) { W=Wak; bsrc=bak; cols=24;  col=n-456; }
    else if (n < 608) { W=Wbk; bsrc=bbk; cols=128; col=n-480; }
    else if (n < 632) { W=Wav; bsrc=bav; cols=24;  col=n-608; }
    else if (n < 760) { W=Wbv; bsrc=bbv; cols=128; col=n-632; }
    for (int k = t; k < 768; k += 256) {
        WcatT[(size_t)n*768 + k] = W ? (_Float16)W[(size_t)k*cols + col] : (_Float16)0.f;
        WoT[(size_t)n*768 + k]   = (_Float16)Wo[(size_t)k*768 + n];
    }
    if (t == 0) bcat[n] = W ? bsrc[col] : 0.f;
}

// ---------------------------------------------------------------------------
// MFMA GEMM: C(Mx768) = A(Mx768) @ BT(768n x 768k)^T + bias, fp32 out.
// 128x128 tile, BK=32, 4 waves, each 64x64 via 4x4 mfma_f32_16x16x32_f16.
// MODE 0: A fp32 (x, converted in staging), epilogue bias+rope, store fp32 P.
// MODE 1: A fp16 (O),                      epilogue bias,      store fp32 Y.
// ---------------------------------------------------------------------------
template<int MODE>
__global__ __launch_bounds__(256) void mfma_gemm(
    const void* __restrict__ Aptr,
    const _Float16* __restrict__ BT,
    const float* __restrict__ bias,
    const float* __restrict__ rope,
    float* __restrict__ C)
{
    const int t = threadIdx.x;
    const int lane = t & 63;
    const int wave = t >> 6;
    const int row0 = blockIdx.y * 128;
    const int col0 = blockIdx.x * 128;
    const int wrow = (wave >> 1) * 64;
    const int wcol = (wave & 1) * 64;

    __shared__ v8h As[512];   // index = kc*128 + row   (kc: 8-wide k-chunk 0..3)
    __shared__ v8h Bs[512];   // index = kc*128 + n

    v4f acc[4][4];
    #pragma unroll
    for (int i = 0; i < 4; ++i)
        #pragma unroll
        for (int j = 0; j < 4; ++j)
            acc[i][j] = (v4f){0.f, 0.f, 0.f, 0.f};

    const v8h* gB = (const v8h*)BT;            // row stride 96 chunks
    const float4* gA32 = (const float4*)Aptr;  // row stride 192 float4s
    const v8h* gA16 = (const v8h*)Aptr;        // row stride 96 chunks

    const int arow = t >> 2;   // 0..63
    const int akc  = t & 3;

    const int q = lane >> 4;   // k-chunk for fragments
    const int m = lane & 15;

    for (int k0 = 0; k0 < 768; k0 += 32) {
        __syncthreads();
        #pragma unroll
        for (int rh = 0; rh < 2; ++rh) {
            const int row = arow + rh*64;
            if (MODE == 0) {
                float4 f0 = gA32[(size_t)(row0 + row)*192 + (k0>>2) + akc*2];
                float4 f1 = gA32[(size_t)(row0 + row)*192 + (k0>>2) + akc*2 + 1];
                v8h h;
                h[0]=(_Float16)f0.x; h[1]=(_Float16)f0.y; h[2]=(_Float16)f0.z; h[3]=(_Float16)f0.w;
                h[4]=(_Float16)f1.x; h[5]=(_Float16)f1.y; h[6]=(_Float16)f1.z; h[7]=(_Float16)f1.w;
                As[akc*128 + row] = h;
            } else {
                As[akc*128 + row] = gA16[(size_t)(row0 + row)*96 + (k0>>3) + akc];
            }
            Bs[akc*128 + row] = gB[(size_t)(col0 + row)*96 + (k0>>3) + akc];
        }
        __syncthreads();

        v8h af[4], bf[4];
        #pragma unroll
        for (int mi = 0; mi < 4; ++mi)
            af[mi] = As[q*128 + wrow + mi*16 + m];
        #pragma unroll
        for (int ni = 0; ni < 4; ++ni)
            bf[ni] = Bs[q*128 + wcol + ni*16 + m];
        #pragma unroll
        for (int mi = 0; mi < 4; ++mi)
            #pragma unroll
            for (int ni = 0; ni < 4; ++ni)
                acc[mi][ni] = __builtin_amdgcn_mfma_f32_16x16x32_f16(
                    af[mi], bf[ni], acc[mi][ni], 0, 0, 0);
    }

    // Epilogue. C/D layout: col = lane&15, row = (lane>>4)*4 + reg.
    #pragma unroll
    for (int mi = 0; mi < 4; ++mi) {
        #pragma unroll
        for (int i = 0; i < 4; ++i) {
            const int grow = row0 + wrow + mi*16 + q*4 + i;
            #pragma unroll
            for (int ni = 0; ni < 4; ++ni) {
                const int gcol = col0 + wcol + ni*16 + m;
                float v = acc[mi][ni][i] + bias[gcol];
                if (MODE == 0) {
                    const int s = grow & 4095;
                    if (gcol >= 72 && gcol < 456)
                        v *= rope[s*64 + ((gcol - 72) & 63)];
                    else if (gcol >= 480 && gcol < 608)
                        v *= rope[s*64 + ((gcol - 480) & 63)];
                }
                C[(size_t)grow*768 + gcol] = v;
            }
        }
    }
}

// ---------------------------------------------------------------------------
// Per-position tensor product + head-attention (rope already applied in P).
// One block (256 threads) per position. Reads fp32 P row, writes fp16 O with
// layout [b][h][s][d] (flat == transpose(0,2,1,3).reshape view).
// ---------------------------------------------------------------------------
#define QS 65
#define SS 13
__global__ __launch_bounds__(256) void tpa_attn(
    const float* __restrict__ P,
    _Float16* __restrict__ O)
{
    const int pos = blockIdx.x;
    const int b = pos >> 12;
    const int s = pos & 4095;
    const int t = threadIdx.x;

    __shared__ float proj[768];
    __shared__ float Qs[NH*QS];
    __shared__ float Ks[NH*QS];
    __shared__ float Vs[NH*QS];
    __shared__ float sc[NH*SS];

    {
        const float4* g = (const float4*)P + (size_t)pos*192;
        if (t < 192) {
            float4 u = g[t];
            proj[t*4+0] = u.x; proj[t*4+1] = u.y;
            proj[t*4+2] = u.z; proj[t*4+3] = u.w;
        }
    }
    __syncthreads();

    const float* aq = proj;
    const float* bq = proj + 72;
    const float* ak = proj + 456;
    const float* bk = proj + 480;
    const float* av = proj + 608;
    const float* bv = proj + 632;

    // tensor products: Q/K/V[h][d] = sum_r A[r][h]*B[r][d]
    for (int j = t; j < NH*DK; j += 256) {
        int h = j >> 6, d = j & 63;
        float qv = 0.f, kv = 0.f, vv = 0.f;
        #pragma unroll
        for (int r = 0; r < RQ; ++r) qv = fmaf(aq[r*NH + h], bq[r*DK + d], qv);
        #pragma unroll
        for (int r = 0; r < RK; ++r) kv = fmaf(ak[r*NH + h], bk[r*DK + d], kv);
        #pragma unroll
        for (int r = 0; r < RV; ++r) vv = fmaf(av[r*NH + h], bv[r*DK + d], vv);
        Qs[h*QS + d] = qv; Ks[h*QS + d] = kv; Vs[h*QS + d] = vv;
    }
    __syncthreads();

    if (t < NH*NH) {
        int h = t / NH, g = t % NH;
        float acc = 0.f;
        #pragma unroll
        for (int d = 0; d < DK; ++d) acc = fmaf(Qs[h*QS+d], Ks[g*QS+d], acc);
        sc[h*SS + g] = acc * 0.125f;
    }
    __syncthreads();

    if (t < NH) {
        float mx = -1e30f;
        for (int g = 0; g < NH; ++g) mx = fmaxf(mx, sc[t*SS+g]);
        float sum = 0.f;
        for (int g = 0; g < NH; ++g) { float e = __expf(sc[t*SS+g]-mx); sc[t*SS+g] = e; sum += e; }
        float inv = 1.0f / sum;
        for (int g = 0; g < NH; ++g) sc[t*SS+g] *= inv;
    }
    __syncthreads();

    for (int j = t; j < NH*DK; j += 256) {
        int h = j >> 6, d = j & 63;
        float acc = 0.f;
        #pragma unroll
        for (int g = 0; g < NH; ++g) acc = fmaf(sc[h*SS+g], Vs[g*QS+d], acc);
        O[((size_t)b*NH + h)*SEQ*DK + (size_t)s*DK + d] = (_Float16)acc;
    }
}

extern "C" void kernel_launch(void* const* d_in, const int* in_sizes, int n_in,
                              void* d_out, int out_size, void* d_ws, size_t ws_size,
                              hipStream_t stream) {
    const float* x    = (const float*)d_in[0];
    const float* rope = (const float*)d_in[1];
    const float* Waq  = (const float*)d_in[2];
    const float* baq  = (const float*)d_in[3];
    const float* Wbq  = (const float*)d_in[4];
    const float* bbq  = (const float*)d_in[5];
    const float* Wak  = (const float*)d_in[6];
    const float* bak  = (const float*)d_in[7];
    const float* Wbk  = (const float*)d_in[8];
    const float* bbk  = (const float*)d_in[9];
    const float* Wav  = (const float*)d_in[10];
    const float* bav  = (const float*)d_in[11];
    const float* Wbv  = (const float*)d_in[12];
    const float* bbv  = (const float*)d_in[13];
    const float* Wo   = (const float*)d_in[14];
    const float* bo   = (const float*)d_in[15];

    // ws layout (total ~52.7 MB): fp16 weights + fp16 O
    char* ws = (char*)d_ws;
    _Float16* WcatT = (_Float16*)(ws);                 // 1,179,648 B
    _Float16* WoT   = (_Float16*)(ws + 1179648);       // 1,179,648 B
    float*    bcat  = (float*)(ws + 2359296);          // 3,072 B
    _Float16* O     = (_Float16*)(ws + 2363392);       // 50,331,648 B

    // P (fp32, 32768x768 = exactly out_size floats) lives in d_out; it is
    // fully consumed by tpa_attn before the final GEMM overwrites d_out.
    float* P = (float*)d_out;

    repack<<<768, 256, 0, stream>>>(Waq, baq, Wbq, bbq, Wak, bak, Wbk, bbk,
                                    Wav, bav, Wbv, bbv, Wo, WcatT, WoT, bcat);

    dim3 gg(6, 256);
    mfma_gemm<0><<<gg, 256, 0, stream>>>(x, WcatT, bcat, rope, P);

    tpa_attn<<<NPOS, 256, 0, stream>>>(P, O);

    mfma_gemm<1><<<gg, 256, 0, stream>>>(O, WoT, bo, nullptr, (float*)d_out);
}

// Round 5
// 398.929 us; speedup vs baseline: 11.1222x; 1.1940x over previous
//
#include <hip/hip_runtime.h>
#include <hip/hip_bf16.h>

#define D_MODEL 768
#define NH 12
#define DK 64
#define RQ 6
#define RK 2
#define RV 2
#define BATCH 8
#define SEQ 4096
#define NPOS (BATCH*SEQ)

typedef _Float16 v8h __attribute__((ext_vector_type(8)));
typedef float v4f __attribute__((ext_vector_type(4)));

// ---------------------------------------------------------------------------
// Repack (fp32 -> fp16): WcatT[n][k] = concat-weights transposed, bcat[n] fp32;
// WoT[n][k] = Wo[k][n]. n in [760,768) zero-padded.
// ---------------------------------------------------------------------------
__global__ __launch_bounds__(256) void repack(
    const float* __restrict__ Waq, const float* __restrict__ baq,
    const float* __restrict__ Wbq, const float* __restrict__ bbq,
    const float* __restrict__ Wak, const float* __restrict__ bak,
    const float* __restrict__ Wbk, const float* __restrict__ bbk,
    const float* __restrict__ Wav, const float* __restrict__ bav,
    const float* __restrict__ Wbv, const float* __restrict__ bbv,
    const float* __restrict__ Wo,
    _Float16* __restrict__ WcatT, _Float16* __restrict__ WoT,
    float* __restrict__ bcat)
{
    const int n = blockIdx.x;   // 0..767
    const int t = threadIdx.x;
    const float* W = nullptr; const float* bsrc = nullptr;
    int cols = 0, col = 0;
    if      (n <  72) { W=Waq; bsrc=baq; cols=72;  col=n;     }
    else if (n < 456) { W=Wbq; bsrc=bbq; cols=384; col=n-72;  }
    else if (n < 480) { W=Wak; bsrc=bak; cols=24;  col=n-456; }
    else if (n < 608) { W=Wbk; bsrc=bbk; cols=128; col=n-480; }
    else if (n < 632) { W=Wav; bsrc=bav; cols=24;  col=n-608; }
    else if (n < 760) { W=Wbv; bsrc=bbv; cols=128; col=n-632; }
    for (int k = t; k < 768; k += 256) {
        WcatT[(size_t)n*768 + k] = W ? (_Float16)W[(size_t)k*cols + col] : (_Float16)0.f;
        WoT[(size_t)n*768 + k]   = (_Float16)Wo[(size_t)k*768 + n];
    }
    if (t == 0) bcat[n] = W ? bsrc[col] : 0.f;
}

// ---------------------------------------------------------------------------
// MFMA GEMM: C(Mx768) = A(Mx768) @ BT(768n x 768k)^T + bias, fp32 out.
// 128x128 tile, BK=32, 4 waves, each 64x64 via 4x4 mfma_f32_16x16x32_f16.
// XCD swizzle: the 6 col-blocks sharing a row tile get the same (flat&7) so
// they land on one XCD (round-robin dispatch) -> A-tile L2 reuse.
// LDS chunk stride padded 128->129 to halve staging-write bank conflicts.
// MODE 0: A fp32 (x, converted in staging), epilogue bias+rope, store fp32 P.
// MODE 1: A fp16 (O),                       epilogue bias,      store fp32 Y.
// ---------------------------------------------------------------------------
#define LSTR 129
template<int MODE>
__global__ __launch_bounds__(256) void mfma_gemm(
    const void* __restrict__ Aptr,
    const _Float16* __restrict__ BT,
    const float* __restrict__ bias,
    const float* __restrict__ rope,
    float* __restrict__ C)
{
    const int t = threadIdx.x;
    const int lane = t & 63;
    const int wave = t >> 6;

    // XCD-aware swizzle of the 1536-block grid (6 x 256)
    const int flat = blockIdx.y * 6 + blockIdx.x;
    const int xcd = flat & 7;
    const int sub = flat >> 3;          // 0..191
    const int ct  = sub % 6;
    const int rt  = xcd * 32 + sub / 6; // 0..255
    const int row0 = rt * 128;
    const int col0 = ct * 128;

    const int wrow = (wave >> 1) * 64;
    const int wcol = (wave & 1) * 64;

    __shared__ v8h As[4*LSTR];   // index = kc*LSTR + row
    __shared__ v8h Bs[4*LSTR];   // index = kc*LSTR + n

    v4f acc[4][4];
    #pragma unroll
    for (int i = 0; i < 4; ++i)
        #pragma unroll
        for (int j = 0; j < 4; ++j)
            acc[i][j] = (v4f){0.f, 0.f, 0.f, 0.f};

    const v8h* gB = (const v8h*)BT;            // row stride 96 chunks
    const float4* gA32 = (const float4*)Aptr;  // row stride 192 float4s
    const v8h* gA16 = (const v8h*)Aptr;        // row stride 96 chunks

    const int arow = t >> 2;   // 0..63
    const int akc  = t & 3;

    const int q = lane >> 4;   // k-chunk for fragments
    const int m = lane & 15;

    for (int k0 = 0; k0 < 768; k0 += 32) {
        __syncthreads();
        #pragma unroll
        for (int rh = 0; rh < 2; ++rh) {
            const int row = arow + rh*64;
            if (MODE == 0) {
                float4 f0 = gA32[(size_t)(row0 + row)*192 + (k0>>2) + akc*2];
                float4 f1 = gA32[(size_t)(row0 + row)*192 + (k0>>2) + akc*2 + 1];
                v8h h;
                h[0]=(_Float16)f0.x; h[1]=(_Float16)f0.y; h[2]=(_Float16)f0.z; h[3]=(_Float16)f0.w;
                h[4]=(_Float16)f1.x; h[5]=(_Float16)f1.y; h[6]=(_Float16)f1.z; h[7]=(_Float16)f1.w;
                As[akc*LSTR + row] = h;
            } else {
                As[akc*LSTR + row] = gA16[(size_t)(row0 + row)*96 + (k0>>3) + akc];
            }
            Bs[akc*LSTR + row] = gB[(size_t)(col0 + row)*96 + (k0>>3) + akc];
        }
        __syncthreads();

        v8h af[4], bf[4];
        #pragma unroll
        for (int mi = 0; mi < 4; ++mi)
            af[mi] = As[q*LSTR + wrow + mi*16 + m];
        #pragma unroll
        for (int ni = 0; ni < 4; ++ni)
            bf[ni] = Bs[q*LSTR + wcol + ni*16 + m];
        #pragma unroll
        for (int mi = 0; mi < 4; ++mi)
            #pragma unroll
            for (int ni = 0; ni < 4; ++ni)
                acc[mi][ni] = __builtin_amdgcn_mfma_f32_16x16x32_f16(
                    af[mi], bf[ni], acc[mi][ni], 0, 0, 0);
    }

    // Epilogue. C/D layout: col = lane&15, row = (lane>>4)*4 + reg.
    #pragma unroll
    for (int mi = 0; mi < 4; ++mi) {
        #pragma unroll
        for (int i = 0; i < 4; ++i) {
            const int grow = row0 + wrow + mi*16 + q*4 + i;
            #pragma unroll
            for (int ni = 0; ni < 4; ++ni) {
                const int gcol = col0 + wcol + ni*16 + m;
                float v = acc[mi][ni][i] + bias[gcol];
                if (MODE == 0) {
                    const int s = grow & 4095;
                    if (gcol >= 72 && gcol < 456)
                        v *= rope[s*64 + ((gcol - 72) & 63)];
                    else if (gcol >= 480 && gcol < 608)
                        v *= rope[s*64 + ((gcol - 480) & 63)];
                }
                C[(size_t)grow*768 + gcol] = v;
            }
        }
    }
}

// ---------------------------------------------------------------------------
// Factorized per-position attention (rope already in P).
//   G[r,r'] = (bq_r . bk_r')/8          (6x2 Gram)
//   scores[h,g] = sum_r aq[r,h] * (G[r,0]ak[0,g] + G[r,1]ak[1,g])
//   attn = softmax_g(scores)
//   c[h,r'] = sum_g attn[h,g] av[r',g]
//   out[h,d] = c[h,0] bv[0,d] + c[h,1] bv[1,d]
// Never materializes Q/K/V. 8 positions per 256-thread block. O fp16,
// layout [b][h][s][d] (flat == transpose(0,2,1,3).reshape view).
// ---------------------------------------------------------------------------
__global__ __launch_bounds__(256) void tpa_attn_f(
    const float* __restrict__ P,
    _Float16* __restrict__ O)
{
    const int t = threadIdx.x;
    const int pos0 = blockIdx.x * 8;

    __shared__ float proj[8][772];   // row pad 768->772: de-bank positions
    __shared__ float Gs[8][12];
    __shared__ float sc[8][160];     // 12 rows x stride 13
    __shared__ float cs[8][24];

    // load 8 P-rows (float4)
    const float4* gp = (const float4*)P;
    for (int i = t; i < 8*192; i += 256) {
        int p = i / 192, c = i - p*192;
        float4 u = gp[(size_t)(pos0 + p)*192 + c];
        proj[p][c*4+0] = u.x; proj[p][c*4+1] = u.y;
        proj[p][c*4+2] = u.z; proj[p][c*4+3] = u.w;
    }
    __syncthreads();

    // Gram matrix: 8 pos x 12 (r,r') pairs
    if (t < 96) {
        int p = t / 12, u = t - (t/12)*12, r = u >> 1, r2 = u & 1;
        const float* bq = &proj[p][72  + r*64];
        const float* bk = &proj[p][480 + r2*64];
        const int ph = (r*8 + r2*16) & 63;   // stagger start to spread banks
        float acc = 0.f;
        for (int i = 0; i < 64; ++i) {
            int d = (i + ph) & 63;
            acc = fmaf(bq[d], bk[d], acc);
        }
        Gs[p][u] = acc * 0.125f;
    }
    __syncthreads();

    // scores: 8 pos x 144 (h,g)
    for (int i = t; i < 8*144; i += 256) {
        int p = i / 144, v = i - p*144, h = v / 12, g = v - (v/12)*12;
        float s = 0.f;
        #pragma unroll
        for (int r = 0; r < RQ; ++r) {
            float mg = fmaf(Gs[p][r*2+1], proj[p][468 + g],
                            Gs[p][r*2+0] * proj[p][456 + g]);
            s = fmaf(proj[p][r*12 + h], mg, s);
        }
        sc[p][h*13 + g] = s;
    }
    __syncthreads();

    // softmax over g: 96 rows
    if (t < 96) {
        int p = t / 12, h = t - (t/12)*12;
        float* row = &sc[p][h*13];
        float mx = -1e30f;
        #pragma unroll
        for (int g = 0; g < NH; ++g) mx = fmaxf(mx, row[g]);
        float sum = 0.f;
        #pragma unroll
        for (int g = 0; g < NH; ++g) { float e = __expf(row[g]-mx); row[g] = e; sum += e; }
        float inv = 1.0f / sum;
        #pragma unroll
        for (int g = 0; g < NH; ++g) row[g] *= inv;
    }
    __syncthreads();

    // c[h,r'] = attn . av^T : 8 pos x 24
    if (t < 192) {
        int p = t / 24, u = t - (t/24)*24, h = u >> 1, r2 = u & 1;
        float acc = 0.f;
        #pragma unroll
        for (int g = 0; g < NH; ++g)
            acc = fmaf(sc[p][h*13+g], proj[p][608 + r2*12 + g], acc);
        cs[p][h*2 + r2] = acc;
    }
    __syncthreads();

    // out: 8 pos x 768, d fastest for coalesced fp16 stores
    for (int i = t; i < 8*768; i += 256) {
        int p = i / 768, j = i - p*768, h = j >> 6, d = j & 63;
        int pos = pos0 + p, b = pos >> 12, s = pos & 4095;
        float val = fmaf(cs[p][h*2+1], proj[p][632 + 64 + d],
                         cs[p][h*2+0] * proj[p][632 + d]);
        O[(((size_t)b*NH + h)*SEQ + s)*DK + d] = (_Float16)val;
    }
}

extern "C" void kernel_launch(void* const* d_in, const int* in_sizes, int n_in,
                              void* d_out, int out_size, void* d_ws, size_t ws_size,
                              hipStream_t stream) {
    const float* x    = (const float*)d_in[0];
    const float* rope = (const float*)d_in[1];
    const float* Waq  = (const float*)d_in[2];
    const float* baq  = (const float*)d_in[3];
    const float* Wbq  = (const float*)d_in[4];
    const float* bbq  = (const float*)d_in[5];
    const float* Wak  = (const float*)d_in[6];
    const float* bak  = (const float*)d_in[7];
    const float* Wbk  = (const float*)d_in[8];
    const float* bbk  = (const float*)d_in[9];
    const float* Wav  = (const float*)d_in[10];
    const float* bav  = (const float*)d_in[11];
    const float* Wbv  = (const float*)d_in[12];
    const float* bbv  = (const float*)d_in[13];
    const float* Wo   = (const float*)d_in[14];
    const float* bo   = (const float*)d_in[15];

    // ws layout (total ~52.7 MB): fp16 weights + fp16 O
    char* ws = (char*)d_ws;
    _Float16* WcatT = (_Float16*)(ws);                 // 1,179,648 B
    _Float16* WoT   = (_Float16*)(ws + 1179648);       // 1,179,648 B
    float*    bcat  = (float*)(ws + 2359296);          // 3,072 B
    _Float16* O     = (_Float16*)(ws + 2363392);       // 50,331,648 B

    // P (fp32, 32768x768 = exactly out_size floats) lives in d_out; fully
    // consumed by tpa_attn_f before the final GEMM overwrites d_out.
    float* P = (float*)d_out;

    repack<<<768, 256, 0, stream>>>(Waq, baq, Wbq, bbq, Wak, bak, Wbk, bbk,
                                    Wav, bav, Wbv, bbv, Wo, WcatT, WoT, bcat);

    dim3 gg(6, 256);
    mfma_gemm<0><<<gg, 256, 0, stream>>>(x, WcatT, bcat, rope, P);

    tpa_attn_f<<<NPOS/8, 256, 0, stream>>>(P, O);

    mfma_gemm<1><<<gg, 256, 0, stream>>>(O, WoT, bo, nullptr, (float*)d_out);
}